// Round 6
// baseline (472.071 us; speedup 1.0000x reference)
//
#include <hip/hip_runtime.h>
#include <hip/hip_bf16.h>
#include <math.h>

// Problem constants
#define B_   32
#define T_   4096
#define CAT_ 128
#define NE_  512
#define HS_  64

#define CHUNKS_ 32                      // k_main blocks per batch row
#define RPB_ (T_ / CHUNKS_)             // 128 rows per block
#define RPW_ (RPB_ / 4)                 // 32 rows per wave (4 waves/block)

typedef float f4 __attribute__((ext_vector_type(4)));

// ---------------------------------------------------------------------------
// K1: phase A: per-block kq[b] (redundant, L2-hot weights);
//     phase B: stream own 128 rows of x once (2 rows/iter for ILP),
//     online-softmax accumulate, one partial (m,l,acc[512]) per block.
// ---------------------------------------------------------------------------
__global__ __launch_bounds__(256, 4) void k_main(
    const float* __restrict__ x, const float* __restrict__ cat_emb,
    const float* __restrict__ Wq, const float* __restrict__ Wk,
    float* __restrict__ pm, float* __restrict__ pl, float* __restrict__ pacc)
{
    const int blk   = blockIdx.x;        // 0..1023
    const int b     = blk >> 5;
    const int chunk = blk & 31;
    const int tid   = threadIdx.x;
    const int wave  = tid >> 6;
    const int lane  = tid & 63;

    __shared__ float sq[HS_];
    __shared__ float skq[NE_];
    __shared__ float red[256];
    __shared__ float sacc[4 * NE_];
    __shared__ float smw[4], slw[4];

    // ---- phase A: kq[n] = 0.125 * Wk[n,:] . (cat_emb[b,:] @ Wq)
    {
        const int h = tid & 63, cq = tid >> 6;
        float qp = 0.f;
        #pragma unroll 8
        for (int c = cq * 32; c < cq * 32 + 32; ++c)
            qp += cat_emb[b * CAT_ + c] * Wq[c * HS_ + h];
        red[tid] = qp;
        __syncthreads();
        if (tid < 64) sq[tid] = red[tid] + red[tid + 64] + red[tid + 128] + red[tid + 192];
        __syncthreads();
        const f4* Wk4 = (const f4*)Wk;
        const f4* sq4 = (const f4*)sq;
        #pragma unroll
        for (int half = 0; half < 2; ++half) {
            const int n = tid + half * 256;
            float acc = 0.f;
            #pragma unroll
            for (int i = 0; i < HS_ / 4; ++i) {
                const f4 w = Wk4[n * (HS_ / 4) + i];
                const f4 s = sq4[i];
                acc += w.x * s.x + w.y * s.y + w.z * s.z + w.w * s.w;
            }
            skq[n] = acc * 0.125f;       // scale = 1/sqrt(64)
        }
        __syncthreads();
    }

    // ---- phase B: stream + online softmax, 2 rows per iteration
    {
        const f4* kq4 = (const f4*)skq;
        const f4 kq0 = kq4[lane];
        const f4 kq1 = kq4[lane + 64];
        const float* xbase = x + (size_t)b * T_ * NE_;
        const int t0 = chunk * RPB_ + wave * RPW_;

        float m = -INFINITY, l = 0.f;
        float a00 = 0.f, a01 = 0.f, a02 = 0.f, a03 = 0.f;
        float a10 = 0.f, a11 = 0.f, a12 = 0.f, a13 = 0.f;

        for (int r = 0; r < RPW_; r += 2) {
            const f4* xrA = (const f4*)(xbase + (size_t)(t0 + r) * NE_);
            const f4* xrB = (const f4*)(xbase + (size_t)(t0 + r + 1) * NE_);
            const f4 xa0 = __builtin_nontemporal_load(&xrA[lane]);
            const f4 xa1 = __builtin_nontemporal_load(&xrA[lane + 64]);
            const f4 xb0 = __builtin_nontemporal_load(&xrB[lane]);
            const f4 xb1 = __builtin_nontemporal_load(&xrB[lane + 64]);
            float pa = xa0.x * kq0.x + xa0.y * kq0.y + xa0.z * kq0.z + xa0.w * kq0.w
                     + xa1.x * kq1.x + xa1.y * kq1.y + xa1.z * kq1.z + xa1.w * kq1.w;
            float pb = xb0.x * kq0.x + xb0.y * kq0.y + xb0.z * kq0.z + xb0.w * kq0.w
                     + xb1.x * kq1.x + xb1.y * kq1.y + xb1.z * kq1.z + xb1.w * kq1.w;
            #pragma unroll
            for (int off = 32; off >= 1; off >>= 1) {
                pa += __shfl_xor(pa, off, 64);
                pb += __shfl_xor(pb, off, 64);
            }
            const float nm = fmaxf(fmaxf(m, pa), pb);   // v_max3
            const float f  = __expf(m - nm);            // 0 on first pair
            const float wa = __expf(pa - nm);
            const float wb = __expf(pb - nm);
            m = nm;
            l = l * f + wa + wb;
            a00 = a00 * f + wa * xa0.x + wb * xb0.x;
            a01 = a01 * f + wa * xa0.y + wb * xb0.y;
            a02 = a02 * f + wa * xa0.z + wb * xb0.z;
            a03 = a03 * f + wa * xa0.w + wb * xb0.w;
            a10 = a10 * f + wa * xa1.x + wb * xb1.x;
            a11 = a11 * f + wa * xa1.y + wb * xb1.y;
            a12 = a12 * f + wa * xa1.z + wb * xb1.z;
            a13 = a13 * f + wa * xa1.w + wb * xb1.w;
        }

        if (lane == 0) { smw[wave] = m; slw[wave] = l; }
        f4* sa = (f4*)(sacc + wave * NE_);
        f4 v0; v0.x = a00; v0.y = a01; v0.z = a02; v0.w = a03;
        f4 v1; v1.x = a10; v1.y = a11; v1.z = a12; v1.w = a13;
        sa[lane]      = v0;
        sa[lane + 64] = v1;
        __syncthreads();

        const float Mb = fmaxf(fmaxf(smw[0], smw[1]), fmaxf(smw[2], smw[3]));
        const float f0 = __expf(smw[0] - Mb), f1 = __expf(smw[1] - Mb);
        const float f2 = __expf(smw[2] - Mb), f3 = __expf(smw[3] - Mb);
        float* dst = pacc + (size_t)blk * NE_;
        dst[tid]       = f0 * sacc[tid]               + f1 * sacc[NE_ + tid]
                       + f2 * sacc[2 * NE_ + tid]     + f3 * sacc[3 * NE_ + tid];
        dst[tid + 256] = f0 * sacc[tid + 256]         + f1 * sacc[NE_ + tid + 256]
                       + f2 * sacc[2 * NE_ + tid + 256] + f3 * sacc[3 * NE_ + tid + 256];
        if (tid == 0) {
            pm[blk] = Mb;
            pl[blk] = f0 * slw[0] + f1 * slw[1] + f2 * slw[2] + f3 * slw[3];
        }
    }
}

// ---------------------------------------------------------------------------
// K2 (fused combine+broadcast): 2048 blocks. Each block redundantly computes
// its b's ynorm (combine 32 partials -> xbar; @Wv; @Wp; LayerNorm) from
// L2-hot pacc/weights, then writes one CONTIGUOUS 128 KB output span.
// ---------------------------------------------------------------------------
__global__ __launch_bounds__(256) void k_tail(
    const float* __restrict__ pm, const float* __restrict__ pl,
    const float* __restrict__ pacc,
    const float* __restrict__ Wv, const float* __restrict__ Wp,
    const float* __restrict__ gamma, const float* __restrict__ beta,
    f4* __restrict__ out4)
{
    const int blk = blockIdx.x;          // 0..2047
    const int b   = blk >> 6;            // 64 blocks per batch row
    const int seg = blk & 63;            // 64 rows each
    const int tid = threadIdx.x;

    __shared__ float spm[CHUNKS_], spl[CHUNKS_], sf[CHUNKS_];
    __shared__ float xbar[NE_];
    __shared__ float sout[HS_];
    __shared__ float red[256];
    __shared__ __align__(16) float yn[NE_];

    if (tid < CHUNKS_) { spm[tid] = pm[b * CHUNKS_ + tid]; spl[tid] = pl[b * CHUNKS_ + tid]; }
    __syncthreads();
    float M = -INFINITY;
    #pragma unroll
    for (int p = 0; p < CHUNKS_; ++p) M = fmaxf(M, spm[p]);
    if (tid < CHUNKS_) sf[tid] = __expf(spm[tid] - M);
    __syncthreads();
    float L = 0.f;
    #pragma unroll
    for (int p = 0; p < CHUNKS_; ++p) L += sf[p] * spl[p];
    const float rL = 1.f / L;

    float x0 = 0.f, x1 = 0.f;
    #pragma unroll 4
    for (int p = 0; p < CHUNKS_; ++p) {
        const float f = sf[p];
        const float* a = pacc + (size_t)(b * CHUNKS_ + p) * NE_;
        x0 += f * a[tid];
        x1 += f * a[tid + 256];
    }
    xbar[tid] = x0 * rL;
    xbar[tid + 256] = x1 * rL;
    __syncthreads();

    // out[h] = sum_n xbar[n] * Wv[n,h]
    const int h = tid & 63, sq4 = tid >> 6;
    float o = 0.f;
    #pragma unroll 8
    for (int i = 0; i < NE_ / 4; ++i) {
        const int nn = sq4 * (NE_ / 4) + i;
        o += xbar[nn] * Wv[nn * HS_ + h];
    }
    red[tid] = o;
    __syncthreads();
    if (tid < 64) sout[tid] = red[tid] + red[tid + 64] + red[tid + 128] + red[tid + 192];
    __syncthreads();

    // y[n] = sum_h sout[h] * Wp[h,n]
    float y0 = 0.f, y1 = 0.f;
    #pragma unroll 8
    for (int hh = 0; hh < HS_; ++hh) {
        const float oh = sout[hh];
        y0 += oh * Wp[hh * NE_ + tid];
        y1 += oh * Wp[hh * NE_ + tid + 256];
    }

    // LayerNorm over 512
    red[tid] = y0 + y1;
    __syncthreads();
    for (int s = 128; s > 0; s >>= 1) { if (tid < s) red[tid] += red[tid + s]; __syncthreads(); }
    const float mu = red[0] * (1.f / NE_);
    __syncthreads();
    const float d0 = y0 - mu, d1 = y1 - mu;
    red[tid] = d0 * d0 + d1 * d1;
    __syncthreads();
    for (int s = 128; s > 0; s >>= 1) { if (tid < s) red[tid] += red[tid + s]; __syncthreads(); }
    const float rstd = rsqrtf(red[0] * (1.f / NE_) + 1e-5f);
    yn[tid]       = d0 * rstd * gamma[tid]       + beta[tid];
    yn[tid + 256] = d1 * rstd * gamma[tid + 256] + beta[tid + 256];
    __syncthreads();

    // broadcast: contiguous 64-row span, nontemporal
    const f4* yn4 = (const f4*)yn;
    const f4 v = yn4[tid & 127];         // (tid + i*256) & 127 == tid & 127
    const size_t base = ((size_t)b * T_ + (size_t)seg * 64) * (NE_ / 4);
    f4* p = out4 + base + tid;
    #pragma unroll 8
    for (int i = 0; i < 32; ++i) {
        __builtin_nontemporal_store(v, p + (size_t)i * 256);
    }
}

// ---------------------------------------------------------------------------
extern "C" void kernel_launch(void* const* d_in, const int* in_sizes, int n_in,
                              void* d_out, int out_size, void* d_ws, size_t ws_size,
                              hipStream_t stream) {
    const float* x       = (const float*)d_in[0];
    const float* cat_emb = (const float*)d_in[1];
    const float* Wq      = (const float*)d_in[2];
    const float* Wk      = (const float*)d_in[3];
    const float* Wv      = (const float*)d_in[4];
    const float* Wp      = (const float*)d_in[5];
    const float* gamma   = (const float*)d_in[6];
    const float* beta    = (const float*)d_in[7];
    float* out = (float*)d_out;

    float* ws   = (float*)d_ws;
    float* pm   = ws;                                  // 1024
    float* pl   = pm + B_ * CHUNKS_;                   // 1024
    float* pacc = pl + B_ * CHUNKS_;                   // 1024*512

    k_main<<<B_ * CHUNKS_, 256, 0, stream>>>(x, cat_emb, Wq, Wk, pm, pl, pacc);
    k_tail<<<2048, 256, 0, stream>>>(pm, pl, pacc, Wv, Wp, gamma, beta, (f4*)out);
}

// Round 9
// 470.619 us; speedup vs baseline: 1.0031x; 1.0031x over previous
//
#include <hip/hip_runtime.h>
#include <hip/hip_bf16.h>
#include <math.h>

// Problem constants
#define B_   32
#define T_   4096
#define CAT_ 128
#define NE_  512
#define HS_  64

#define CHUNKS_ 32                      // k_main blocks per batch row
#define RPB_ (T_ / CHUNKS_)             // 128 rows per block
#define RPW_ (RPB_ / 4)                 // 32 rows per wave (4 waves/block)

typedef float f4 __attribute__((ext_vector_type(4)));

// ---------------------------------------------------------------------------
// K1: phase A: per-block kq[b] (redundant, L2-hot weights);
//     phase B: stream own 128 rows of x once (2 rows/iter for ILP),
//     online-softmax accumulate, one partial (m,l,acc[512]) per block.
// ---------------------------------------------------------------------------
__global__ __launch_bounds__(256, 4) void k_main(
    const float* __restrict__ x, const float* __restrict__ cat_emb,
    const float* __restrict__ Wq, const float* __restrict__ Wk,
    float* __restrict__ pm, float* __restrict__ pl, float* __restrict__ pacc)
{
    const int blk   = blockIdx.x;        // 0..1023
    const int b     = blk >> 5;
    const int chunk = blk & 31;
    const int tid   = threadIdx.x;
    const int wave  = tid >> 6;
    const int lane  = tid & 63;

    __shared__ float sq[HS_];
    __shared__ float skq[NE_];
    __shared__ float red[256];
    __shared__ float sacc[4 * NE_];
    __shared__ float smw[4], slw[4];

    // ---- phase A: kq[n] = 0.125 * Wk[n,:] . (cat_emb[b,:] @ Wq)
    {
        const int h = tid & 63, cq = tid >> 6;
        float qp = 0.f;
        #pragma unroll 8
        for (int c = cq * 32; c < cq * 32 + 32; ++c)
            qp += cat_emb[b * CAT_ + c] * Wq[c * HS_ + h];
        red[tid] = qp;
        __syncthreads();
        if (tid < 64) sq[tid] = red[tid] + red[tid + 64] + red[tid + 128] + red[tid + 192];
        __syncthreads();
        const f4* Wk4 = (const f4*)Wk;
        const f4* sq4 = (const f4*)sq;
        #pragma unroll
        for (int half = 0; half < 2; ++half) {
            const int n = tid + half * 256;
            float acc = 0.f;
            #pragma unroll
            for (int i = 0; i < HS_ / 4; ++i) {
                const f4 w = Wk4[n * (HS_ / 4) + i];
                const f4 s = sq4[i];
                acc += w.x * s.x + w.y * s.y + w.z * s.z + w.w * s.w;
            }
            skq[n] = acc * 0.125f;       // scale = 1/sqrt(64)
        }
        __syncthreads();
    }

    // ---- phase B: stream + online softmax, 2 rows per iteration
    {
        const f4* kq4 = (const f4*)skq;
        const f4 kq0 = kq4[lane];
        const f4 kq1 = kq4[lane + 64];
        const float* xbase = x + (size_t)b * T_ * NE_;
        const int t0 = chunk * RPB_ + wave * RPW_;

        float m = -INFINITY, l = 0.f;
        float a00 = 0.f, a01 = 0.f, a02 = 0.f, a03 = 0.f;
        float a10 = 0.f, a11 = 0.f, a12 = 0.f, a13 = 0.f;

        for (int r = 0; r < RPW_; r += 2) {
            const f4* xrA = (const f4*)(xbase + (size_t)(t0 + r) * NE_);
            const f4* xrB = (const f4*)(xbase + (size_t)(t0 + r + 1) * NE_);
            const f4 xa0 = __builtin_nontemporal_load(&xrA[lane]);
            const f4 xa1 = __builtin_nontemporal_load(&xrA[lane + 64]);
            const f4 xb0 = __builtin_nontemporal_load(&xrB[lane]);
            const f4 xb1 = __builtin_nontemporal_load(&xrB[lane + 64]);
            float pa = xa0.x * kq0.x + xa0.y * kq0.y + xa0.z * kq0.z + xa0.w * kq0.w
                     + xa1.x * kq1.x + xa1.y * kq1.y + xa1.z * kq1.z + xa1.w * kq1.w;
            float pb = xb0.x * kq0.x + xb0.y * kq0.y + xb0.z * kq0.z + xb0.w * kq0.w
                     + xb1.x * kq1.x + xb1.y * kq1.y + xb1.z * kq1.z + xb1.w * kq1.w;
            #pragma unroll
            for (int off = 32; off >= 1; off >>= 1) {
                pa += __shfl_xor(pa, off, 64);
                pb += __shfl_xor(pb, off, 64);
            }
            const float nm = fmaxf(fmaxf(m, pa), pb);   // v_max3
            const float f  = __expf(m - nm);            // 0 on first pair
            const float wa = __expf(pa - nm);
            const float wb = __expf(pb - nm);
            m = nm;
            l = l * f + wa + wb;
            a00 = a00 * f + wa * xa0.x + wb * xb0.x;
            a01 = a01 * f + wa * xa0.y + wb * xb0.y;
            a02 = a02 * f + wa * xa0.z + wb * xb0.z;
            a03 = a03 * f + wa * xa0.w + wb * xb0.w;
            a10 = a10 * f + wa * xa1.x + wb * xb1.x;
            a11 = a11 * f + wa * xa1.y + wb * xb1.y;
            a12 = a12 * f + wa * xa1.z + wb * xb1.z;
            a13 = a13 * f + wa * xa1.w + wb * xb1.w;
        }

        if (lane == 0) { smw[wave] = m; slw[wave] = l; }
        f4* sa = (f4*)(sacc + wave * NE_);
        f4 v0; v0.x = a00; v0.y = a01; v0.z = a02; v0.w = a03;
        f4 v1; v1.x = a10; v1.y = a11; v1.z = a12; v1.w = a13;
        sa[lane]      = v0;
        sa[lane + 64] = v1;
        __syncthreads();

        const float Mb = fmaxf(fmaxf(smw[0], smw[1]), fmaxf(smw[2], smw[3]));
        const float f0 = __expf(smw[0] - Mb), f1 = __expf(smw[1] - Mb);
        const float f2 = __expf(smw[2] - Mb), f3 = __expf(smw[3] - Mb);
        float* dst = pacc + (size_t)blk * NE_;
        dst[tid]       = f0 * sacc[tid]               + f1 * sacc[NE_ + tid]
                       + f2 * sacc[2 * NE_ + tid]     + f3 * sacc[3 * NE_ + tid];
        dst[tid + 256] = f0 * sacc[tid + 256]         + f1 * sacc[NE_ + tid + 256]
                       + f2 * sacc[2 * NE_ + tid + 256] + f3 * sacc[3 * NE_ + tid + 256];
        if (tid == 0) {
            pm[blk] = Mb;
            pl[blk] = f0 * slw[0] + f1 * slw[1] + f2 * slw[2] + f3 * slw[3];
        }
    }
}

// ---------------------------------------------------------------------------
// K2: per batch row: combine 32 partials -> xbar; xbar@Wv; @Wp; LayerNorm.
// (runs once per b, 32 blocks, ~5 µs)
// ---------------------------------------------------------------------------
__global__ __launch_bounds__(256) void k_combine(const float* __restrict__ pm,
                                                 const float* __restrict__ pl,
                                                 const float* __restrict__ pacc,
                                                 const float* __restrict__ Wv,
                                                 const float* __restrict__ Wp,
                                                 const float* __restrict__ gamma,
                                                 const float* __restrict__ beta,
                                                 float* __restrict__ ynorm) {
    const int b   = blockIdx.x;
    const int tid = threadIdx.x;
    __shared__ float xbar[NE_];
    __shared__ float sout[HS_];
    __shared__ float red[256];

    float M = -INFINITY;
    #pragma unroll
    for (int p = 0; p < CHUNKS_; ++p) M = fmaxf(M, pm[b * CHUNKS_ + p]);
    float L = 0.f, x0 = 0.f, x1 = 0.f;
    for (int p = 0; p < CHUNKS_; ++p) {
        const float f = __expf(pm[b * CHUNKS_ + p] - M);
        L += f * pl[b * CHUNKS_ + p];
        const float* a = pacc + (size_t)(b * CHUNKS_ + p) * NE_;
        x0 += f * a[tid];
        x1 += f * a[tid + 256];
    }
    const float rL = 1.f / L;
    xbar[tid] = x0 * rL;
    xbar[tid + 256] = x1 * rL;
    __syncthreads();

    const int h = tid & 63, seg = tid >> 6;
    float o = 0.f;
    #pragma unroll 8
    for (int i = 0; i < NE_ / 4; ++i) {
        const int nn = seg * (NE_ / 4) + i;
        o += xbar[nn] * Wv[nn * HS_ + h];
    }
    red[tid] = o;
    __syncthreads();
    if (tid < 64) sout[tid] = red[tid] + red[tid + 64] + red[tid + 128] + red[tid + 192];
    __syncthreads();

    float y0 = 0.f, y1 = 0.f;
    #pragma unroll 8
    for (int hh = 0; hh < HS_; ++hh) {
        const float oh = sout[hh];
        y0 += oh * Wp[hh * NE_ + tid];
        y1 += oh * Wp[hh * NE_ + tid + 256];
    }

    red[tid] = y0 + y1;
    __syncthreads();
    for (int s = 128; s > 0; s >>= 1) { if (tid < s) red[tid] += red[tid + s]; __syncthreads(); }
    const float mu = red[0] * (1.f / NE_);
    __syncthreads();
    const float d0 = y0 - mu, d1 = y1 - mu;
    red[tid] = d0 * d0 + d1 * d1;
    __syncthreads();
    for (int s = 128; s > 0; s >>= 1) { if (tid < s) red[tid] += red[tid + s]; __syncthreads(); }
    const float rstd = rsqrtf(red[0] * (1.f / NE_) + 1e-5f);
    ynorm[b * NE_ + tid]       = d0 * rstd * gamma[tid]       + beta[tid];
    ynorm[b * NE_ + tid + 256] = d1 * rstd * gamma[tid + 256] + beta[tid + 256];
}

// ---------------------------------------------------------------------------
// K3: pure broadcast. Each block writes one CONTIGUOUS 128 KB span
// (one b, 64 rows), nontemporal streaming stores.
// ---------------------------------------------------------------------------
__global__ __launch_bounds__(256) void k_bcast(const f4* __restrict__ yn4,
                                               f4* __restrict__ out4) {
    const int blk = blockIdx.x;          // 0..2047
    const int b   = blk >> 6;            // 64 blocks per batch row
    const int seg = blk & 63;            // 64 rows each
    const int tid = threadIdx.x;
    const f4 v = yn4[(b << 7) + (tid & 127)];   // (tid + i*256) & 127 == tid & 127
    const size_t base = ((size_t)b * T_ + (size_t)seg * 64) * (NE_ / 4);
    f4* p = out4 + base + tid;
    #pragma unroll 8
    for (int i = 0; i < 32; ++i) {
        __builtin_nontemporal_store(v, p + (size_t)i * 256);
    }
}

// ---------------------------------------------------------------------------
extern "C" void kernel_launch(void* const* d_in, const int* in_sizes, int n_in,
                              void* d_out, int out_size, void* d_ws, size_t ws_size,
                              hipStream_t stream) {
    const float* x       = (const float*)d_in[0];
    const float* cat_emb = (const float*)d_in[1];
    const float* Wq      = (const float*)d_in[2];
    const float* Wk      = (const float*)d_in[3];
    const float* Wv      = (const float*)d_in[4];
    const float* Wp      = (const float*)d_in[5];
    const float* gamma   = (const float*)d_in[6];
    const float* beta    = (const float*)d_in[7];
    float* out = (float*)d_out;

    float* ws    = (float*)d_ws;
    float* pm    = ws;                                 // 1024
    float* pl    = pm + B_ * CHUNKS_;                  // 1024
    float* pacc  = pl + B_ * CHUNKS_;                  // 1024*512
    float* ynorm = pacc + (size_t)B_ * CHUNKS_ * NE_;  // 32*512

    k_main<<<B_ * CHUNKS_, 256, 0, stream>>>(x, cat_emb, Wq, Wk, pm, pl, pacc);
    k_combine<<<B_, 256, 0, stream>>>(pm, pl, pacc, Wv, Wp, gamma, beta, ynorm);
    k_bcast<<<2048, 256, 0, stream>>>((const f4*)ynorm, (f4*)out);
}